// Round 20
// baseline (4050.435 us; speedup 1.0000x reference)
//
#include <hip/hip_runtime.h>
#include <math.h>

#define BB 2
#define NXX 8192
#define NYY 8192
#define CC 256
#define KNN 15
#define KP 20      // per-row candidates by (dot desc, col asc); sim-top-16 provably inside
#define NSLOT 16
#define TAUF 0.2f

#define TM 32
#define TNF 256                 // fast: 4 waves; wave w owns rows 8w..8w+7, 64 lanes x 4 cols
#define NCTF (NYY / TNF)        // 32
#define QW 256                  // per-wave queue: exact bound = 64 lanes * 4 cols (1 row/round)

// slow fallback geometry (R12-proven)
#define KC 32
#define SPAD 132
#define QMAX 1024
#define NKC (CC / KC)
#define NSTAGE ((NYY / 128) * NKC)
#define YSTR 8256               // padded Ynt row stride (floats)

// ---- norms: BYTE-IDENTICAL to round 10 (site-defining, do not touch) ----
__device__ inline float sqf(float v) {
    float p = v * v;
    asm volatile("" : "+v"(p));
    return p;
}

__device__ inline float normsq256(const float* __restrict__ a) {
    float half[2];
#pragma unroll
    for (int h = 0; h < 2; ++h) {
        const float* p = a + h * 128;
        float r[8];
#pragma unroll
        for (int j = 0; j < 8; ++j) r[j] = sqf(p[j]);
#pragma unroll 1
        for (int i = 8; i < 128; i += 8) {
#pragma unroll
            for (int j = 0; j < 8; ++j) r[j] = r[j] + sqf(p[i + j]);
        }
        half[h] = ((r[0] + r[1]) + (r[2] + r[3])) + ((r[4] + r[5]) + (r[6] + r[7]));
    }
    return half[0] + half[1];
}

__global__ __launch_bounds__(256) void norms_kernel(const float* __restrict__ X,
                                                    const float* __restrict__ Y,
                                                    float* __restrict__ nx,
                                                    float* __restrict__ ny) {
    int r = blockIdx.x * 256 + threadIdx.x;
    const float* p;
    float* o;
    if (r < BB * NXX) {
        p = X + (size_t)r * CC;
        o = nx + r;
    } else {
        int q = r - BB * NXX;
        p = Y + (size_t)q * CC;
        o = ny + q;
    }
    float s = normsq256(p);
    float n = __fsqrt_rn(s);
    n = fmaxf(n, 1e-12f);
    *o = n;
}

// ---- transpose + normalize Y into padded layout: Ynt[(b*CC+k)*YSTR + col] ----
__global__ __launch_bounds__(256) void ytranspose(const float* __restrict__ Y,
                                                  const float* __restrict__ ny,
                                                  float* __restrict__ Ynt) {
    __shared__ float tile[64][65];
    const int bid = blockIdx.x;             // b*512 + colT*4 + kT
    const int kT = bid & 3;
    const int colT = (bid >> 2) & 127;
    const int b = bid >> 9;
    const int col0 = colT * 64, k0 = kT * 64;
    const int r = threadIdx.x >> 4;         // 0..15
    const int c = threadIdx.x & 15;         // 0..15

    const float* Yb = Y + ((size_t)b * NYY + col0) * CC + k0;
#pragma unroll
    for (int ii = 0; ii < 4; ++ii) {
        int row = r + ii * 16;              // local col index
        float n = ny[b * NYY + col0 + row];
        float4 v = *(const float4*)(Yb + (size_t)row * CC + c * 4);
        v.x = v.x / n; v.y = v.y / n; v.z = v.z / n; v.w = v.w / n;
        tile[row][c * 4 + 0] = v.x;
        tile[row][c * 4 + 1] = v.y;
        tile[row][c * 4 + 2] = v.z;
        tile[row][c * 4 + 3] = v.w;
    }
    __syncthreads();
    float* D = Ynt + ((size_t)b * CC + k0) * YSTR + col0;
#pragma unroll
    for (int ii = 0; ii < 4; ++ii) {
        int krow = r + ii * 16;             // local k index
        float4 v;
        v.x = tile[c * 4 + 0][krow];
        v.y = tile[c * 4 + 1][krow];
        v.z = tile[c * 4 + 2][krow];
        v.w = tile[c * 4 + 3][krow];
        *(float4*)(D + (size_t)krow * YSTR + c * 4) = v;
    }
    if (colT == 127) {
        for (int i = threadIdx.x; i < 64 * (YSTR - NYY); i += 256) {
            int kr = i / (YSTR - NYY), pc = i % (YSTR - NYY);
            Ynt[((size_t)b * CC + k0 + kr) * YSTR + NYY + pc] = 0.f;
        }
    }
}

// ---- wave-level fence: compiler barrier + drain LDS ops ----
__device__ inline void wave_fence() {
    __builtin_amdgcn_wave_barrier();
    asm volatile("s_waitcnt lgkmcnt(0)" ::: "memory");
    __builtin_amdgcn_wave_barrier();
}

// ================== FAST pass1: 8 rows/thread (half Y traffic), lean queues ==================
#define LOADY4(YQ, PTR)                                                    \
    YQ[0] = *(const float4*)(PTR);                                         \
    YQ[1] = *(const float4*)((PTR) + YSTR);                                \
    YQ[2] = *(const float4*)((PTR) + 2 * YSTR);                            \
    YQ[3] = *(const float4*)((PTR) + 3 * YSTR);

#define FMA8(YQ, K4)                                                       \
    {                                                                      \
        float4 xq[8];                                                      \
        _Pragma("unroll") for (int i = 0; i < 8; ++i)                      \
            xq[i] = *(const float4*)(&Xs[r0 + i][(K4) * 4]);               \
        _Pragma("unroll") for (int kk = 0; kk < 4; ++kk) {                 \
            _Pragma("unroll") for (int i = 0; i < 8; ++i) {                \
                float xv = ((const float*)&xq[i])[kk];                     \
                acc[i][0] = fmaf(xv, YQ[kk].x, acc[i][0]);                 \
                acc[i][1] = fmaf(xv, YQ[kk].y, acc[i][1]);                 \
                acc[i][2] = fmaf(xv, YQ[kk].z, acc[i][2]);                 \
                acc[i][3] = fmaf(xv, YQ[kk].w, acc[i][3]);                 \
            }                                                              \
        }                                                                  \
    }

#define KLOOP_PIPELINED8(YCPTR)                                            \
    float4 y0[4], y1[4], y2[4], y3[4];                                     \
    const float* yp = (YCPTR);                                             \
    LOADY4(y0, yp); yp += 4 * YSTR;                                        \
    LOADY4(y1, yp); yp += 4 * YSTR;                                        \
    LOADY4(y2, yp); yp += 4 * YSTR;                                        \
    LOADY4(y3, yp); yp += 4 * YSTR;                                        \
    _Pragma("unroll 1")                                                    \
    for (int kb = 0; kb < 60; kb += 4) {                                   \
        FMA8(y0, kb + 0); LOADY4(y0, yp); yp += 4 * YSTR;                  \
        FMA8(y1, kb + 1); LOADY4(y1, yp); yp += 4 * YSTR;                  \
        FMA8(y2, kb + 2); LOADY4(y2, yp); yp += 4 * YSTR;                  \
        FMA8(y3, kb + 3); LOADY4(y3, yp); yp += 4 * YSTR;                  \
    }                                                                      \
    FMA8(y0, 60); FMA8(y1, 61); FMA8(y2, 62); FMA8(y3, 63);

__global__ __launch_bounds__(256) void pass1_fast(const float* __restrict__ X,
                                                  const float* __restrict__ nx,
                                                  const float* __restrict__ Ynt,
                                                  float* __restrict__ rowSim,
                                                  int* __restrict__ rowIdx,
                                                  float* __restrict__ rowGap,
                                                  int* __restrict__ rowSlot) {
    __shared__ float Xs[TM][CC];        // 32 KB
    __shared__ float qvS[4][QW];        // 4 KB  (lean: 1 row per round)
    __shared__ int   qmS[4][QW];        // 4 KB
    __shared__ int   qnS[4];
    __shared__ float thrS[4][8];
    __shared__ float topvS[4][8][KP];   // 2.5 KB
    __shared__ int   topiS[4][8][KP];   // 2.5 KB

    const int t = threadIdx.x;
    const int bid = blockIdx.x;          // 0..511
    const int b = bid / (NXX / TM);
    const int rt = bid % (NXX / TM);
    const int row0 = rt * TM;

    const float* Xb = X + ((size_t)b * NXX + row0) * CC;
    // stage X once, normalized: fl(x/n) IEEE division (bit-identical to R10)
#pragma unroll
    for (int i = 0; i < 8; ++i) {
        int lin = i * 256 + t;
        int r = lin >> 6;
        int q = lin & 63;
        float nr = nx[b * NXX + row0 + r];
        float4 v = *(const float4*)(Xb + r * CC + q * 4);
        v.x = v.x / nr; v.y = v.y / nr; v.z = v.z / nr; v.w = v.w / nr;
        *(float4*)(&Xs[r][q * 4]) = v;
    }
    for (int i = t; i < 4 * 8 * KP; i += 256) {
        int wv = i / (8 * KP), rl = (i / KP) & 7, sl = i % KP;
        topvS[wv][rl][sl] = -INFINITY;
        topiS[wv][rl][sl] = 0x7fffffff;
    }
    if (t < 32) thrS[t >> 3][t & 7] = -INFINITY;
    if (t < 4) qnS[t] = 0;
    __syncthreads();

    const int w = t >> 6;                // wave id 0..3; wave owns rows 8w..8w+7
    const int lane = t & 63;
    const int r0 = w * 8;
    const float* Yb = Ynt + (size_t)b * CC * YSTR;

#pragma unroll 1
    for (int ct = 0; ct < NCTF; ++ct) {
        const int c0 = ct * TNF + lane * 4;
        float acc[8][4];
#pragma unroll
        for (int i = 0; i < 8; ++i)
#pragma unroll
            for (int j = 0; j < 4; ++j) acc[i][j] = 0.f;

        KLOOP_PIPELINED8(Yb + c0)

        // ---- per-wave top-k: 8 single-row rounds (push bound 256 = QW) ----
#pragma unroll
        for (int rr = 0; rr < 8; ++rr) {
            float th = thrS[w][rr];
            bool pushed = false;
#pragma unroll
            for (int j = 0; j < 4; ++j) {
                float v = acc[rr][j];
                if (v >= th) {
                    pushed = true;
                    int p = atomicAdd(&qnS[w], 1);
                    if (p < QW) {            // bound exact (<=256); defensive
                        qvS[w][p] = v;
                        qmS[w][p] = (rr << 13) | (c0 + j);
                    }
                }
            }
            if (__ballot(pushed) != 0ull) {
                wave_fence();
                if (lane < 8) {
                    int n = qnS[w];
                    if (n > QW) n = QW;
#pragma unroll 1
                    for (int e = 0; e < n; ++e) {
                        int m = qmS[w][e];
                        if ((m >> 13) == lane) {
                            float v = qvS[w][e];
                            int col = m & 8191;
                            float lv = topvS[w][lane][KP - 1];
                            int li = topiS[w][lane][KP - 1];
                            if (v > lv || (v == lv && col < li)) {
                                int p = KP - 1;
                                while (p > 0 && (topvS[w][lane][p - 1] < v ||
                                       (topvS[w][lane][p - 1] == v && topiS[w][lane][p - 1] > col))) {
                                    topvS[w][lane][p] = topvS[w][lane][p - 1];
                                    topiS[w][lane][p] = topiS[w][lane][p - 1];
                                    --p;
                                }
                                topvS[w][lane][p] = v;
                                topiS[w][lane][p] = col;
                            }
                        }
                    }
                    thrS[w][lane] = topvS[w][lane][KP - 1];
                    if (lane == 0) qnS[w] = 0;
                }
                wave_fence();
            }
        }
    }

    __syncthreads();   // make all waves' top-k lists visible to epilogue lanes

    // epilogue: sim = fl(dot/0.2f); stable select 16 by (sim desc, idx asc); min-gap
    if (t < TM) {
        int gr = b * NXX + row0 + t;
        const int ww = t >> 3, rl = t & 7;
        float simv[KP];
        int id[KP];
        bool used[KP];
#pragma unroll
        for (int j = 0; j < KP; ++j) {
            simv[j] = topvS[ww][rl][j] / TAUF;
            id[j] = topiS[ww][rl][j];
            used[j] = false;
        }
        float sv[NSLOT];
        int si[NSLOT];
#pragma unroll 1
        for (int k = 0; k < NSLOT; ++k) {
            float bv = -INFINITY;
            int bi = 0x7fffffff, bj = 0;
#pragma unroll 1
            for (int j = 0; j < KP; ++j) {
                if (!used[j]) {
                    if (simv[j] > bv || (simv[j] == bv && id[j] < bi)) {
                        bv = simv[j]; bi = id[j]; bj = j;
                    }
                }
            }
            used[bj] = true;
            sv[k] = bv;
            si[k] = bi;
        }
        float mg = INFINITY;
        int ms = 0;
#pragma unroll 1
        for (int sl = 0; sl < KNN; ++sl) {
            float g = sv[sl] - sv[sl + 1];
            if (g > 0.f && g < mg) { mg = g; ms = sl; }
        }
#pragma unroll
        for (int k = 0; k < NSLOT; ++k) {
            rowSim[(size_t)gr * NSLOT + k] = sv[k];
            rowIdx[(size_t)gr * NSLOT + k] = si[k];
        }
        rowGap[gr] = mg;
        rowSlot[gr] = ms;
    }
}

// ================== SLOW fallback pass1 (R12's proven kernel) ==================
__global__ __launch_bounds__(256) void pass1_slow(const float* __restrict__ X,
                                                  const float* __restrict__ Yg,
                                                  const float* __restrict__ nx,
                                                  const float* __restrict__ ny,
                                                  float* __restrict__ rowSim,
                                                  int* __restrict__ rowIdx,
                                                  float* __restrict__ rowGap,
                                                  int* __restrict__ rowSlot) {
    __shared__ float Xs[TM][CC];
    __shared__ float Ys[2][KC][SPAD];
    __shared__ float topv[TM][KP];
    __shared__ int   topi[TM][KP];
    __shared__ float thr[TM];
    __shared__ float qv[QMAX];
    __shared__ int   qm[QMAX];
    __shared__ int   qn;

    const int t = threadIdx.x;
    const int bid = blockIdx.x;
    const int b = bid / (NXX / TM);
    const int rt = bid % (NXX / TM);
    const int row0 = rt * TM;

    const float* Xb = X + ((size_t)b * NXX + row0) * CC;
    const float* Yb = Yg + (size_t)b * NYY * CC;

#pragma unroll
    for (int i = 0; i < 8; ++i) {
        int lin = i * 256 + t;
        int r = lin >> 6;
        int kq4 = lin & 63;
        float4 v = *(const float4*)(Xb + r * CC + kq4 * 4);
        float nr = nx[b * NXX + row0 + r];
        v.x = v.x / nr; v.y = v.y / nr; v.z = v.z / nr; v.w = v.w / nr;
        *(float4*)(&Xs[r][kq4 * 4]) = v;
    }
    for (int i = t; i < TM * KP; i += 256) {
        topv[i / KP][i % KP] = -INFINITY;
        topi[i / KP][i % KP] = 0x7fffffff;
    }
    if (t < TM) thr[t] = -INFINITY;
    if (t == 0) qn = 0;

    const int ty = t >> 5, tx = t & 31;
    const int r0 = ty * 4, c0 = tx * 4;
    const int kq = t & 7;
    const int cst = t >> 3;

    float4 y0, y1, y2, y3;
    {
        const float* base = Yb + (size_t)cst * CC + kq * 4;
        y0 = *(const float4*)(base);
        y1 = *(const float4*)(base + 32 * CC);
        y2 = *(const float4*)(base + 64 * CC);
        y3 = *(const float4*)(base + 96 * CC);
        int cb = b * NYY + cst;
        float n0 = ny[cb], n1 = ny[cb + 32], n2 = ny[cb + 64], n3 = ny[cb + 96];
        y0.x /= n0; y0.y /= n0; y0.z /= n0; y0.w /= n0;
        y1.x /= n1; y1.y /= n1; y1.z /= n1; y1.w /= n1;
        y2.x /= n2; y2.y /= n2; y2.z /= n2; y2.w /= n2;
        y3.x /= n3; y3.y /= n3; y3.z /= n3; y3.w /= n3;
    }
    {
        int sc = cst ^ (4 * kq);
        Ys[0][kq * 4 + 0][sc] = y0.x; Ys[0][kq * 4 + 1][sc] = y0.y;
        Ys[0][kq * 4 + 2][sc] = y0.z; Ys[0][kq * 4 + 3][sc] = y0.w;
        sc = (cst + 32) ^ (4 * kq);
        Ys[0][kq * 4 + 0][sc] = y1.x; Ys[0][kq * 4 + 1][sc] = y1.y;
        Ys[0][kq * 4 + 2][sc] = y1.z; Ys[0][kq * 4 + 3][sc] = y1.w;
        sc = (cst + 64) ^ (4 * kq);
        Ys[0][kq * 4 + 0][sc] = y2.x; Ys[0][kq * 4 + 1][sc] = y2.y;
        Ys[0][kq * 4 + 2][sc] = y2.z; Ys[0][kq * 4 + 3][sc] = y2.w;
        sc = (cst + 96) ^ (4 * kq);
        Ys[0][kq * 4 + 0][sc] = y3.x; Ys[0][kq * 4 + 1][sc] = y3.y;
        Ys[0][kq * 4 + 2][sc] = y3.z; Ys[0][kq * 4 + 3][sc] = y3.w;
    }
    __syncthreads();

    float acc[4][4];
    int cur = 0;

#pragma unroll 1
    for (int s = 0; s < NSTAGE; ++s) {
        const int ct = s >> 3;
        const int kc = s & 7;

        if (s + 1 < NSTAGE) {
            const int ct1 = (s + 1) >> 3;
            const int kc1 = (s + 1) & 7;
            const float* base = Yb + (size_t)(ct1 * 128 + cst) * CC + kc1 * KC + kq * 4;
            y0 = *(const float4*)(base);
            y1 = *(const float4*)(base + 32 * CC);
            y2 = *(const float4*)(base + 64 * CC);
            y3 = *(const float4*)(base + 96 * CC);
            int cb = b * NYY + ct1 * 128 + cst;
            float n0 = ny[cb], n1 = ny[cb + 32], n2 = ny[cb + 64], n3 = ny[cb + 96];
            y0.x /= n0; y0.y /= n0; y0.z /= n0; y0.w /= n0;
            y1.x /= n1; y1.y /= n1; y1.z /= n1; y1.w /= n1;
            y2.x /= n2; y2.y /= n2; y2.z /= n2; y2.w /= n2;
            y3.x /= n3; y3.y /= n3; y3.z /= n3; y3.w /= n3;
        }

        if (kc == 0) {
#pragma unroll
            for (int i = 0; i < 4; ++i)
#pragma unroll
                for (int j = 0; j < 4; ++j) acc[i][j] = 0.f;
        }

#pragma unroll
        for (int k4 = 0; k4 < 8; ++k4) {
            const int swz = 4 * k4;
            float4 xq[4], yq[4];
#pragma unroll
            for (int i = 0; i < 4; ++i)
                xq[i] = *(const float4*)(&Xs[r0 + i][kc * KC + k4 * 4]);
#pragma unroll
            for (int kk = 0; kk < 4; ++kk)
                yq[kk] = *(const float4*)(&Ys[cur][k4 * 4 + kk][c0 ^ swz]);
#pragma unroll
            for (int kk = 0; kk < 4; ++kk) {
#pragma unroll
                for (int i = 0; i < 4; ++i) {
                    float xv = ((const float*)&xq[i])[kk];
                    acc[i][0] = fmaf(xv, yq[kk].x, acc[i][0]);
                    acc[i][1] = fmaf(xv, yq[kk].y, acc[i][1]);
                    acc[i][2] = fmaf(xv, yq[kk].z, acc[i][2]);
                    acc[i][3] = fmaf(xv, yq[kk].w, acc[i][3]);
                }
            }
        }

        if (kc == NKC - 1) {
            const int cbase = ct * 128;
#pragma unroll 1
            for (int rr = 0; rr < 4; ++rr) {
                float th = thr[r0 + rr];
#pragma unroll
                for (int j = 0; j < 4; ++j) {
                    float v = acc[rr][j];
                    if (v >= th) {
                        int p = atomicAdd(&qn, 1);
                        if (p < QMAX) {
                            qv[p] = v;
                            qm[p] = ((r0 + rr) << 13) | (cbase + c0 + j);
                        }
                    }
                }
                __syncthreads();
                if (t < TM) {
                    int n = qn;
                    if (n > QMAX) n = QMAX;
#pragma unroll 1
                    for (int e = 0; e < n; ++e) {
                        int m = qm[e];
                        if ((m >> 13) == t) {
                            float v = qv[e];
                            int col = m & 8191;
                            float lv = topv[t][KP - 1];
                            int li = topi[t][KP - 1];
                            if (v > lv || (v == lv && col < li)) {
                                int p = KP - 1;
                                while (p > 0 && (topv[t][p - 1] < v ||
                                       (topv[t][p - 1] == v && topi[t][p - 1] > col))) {
                                    topv[t][p] = topv[t][p - 1];
                                    topi[t][p] = topi[t][p - 1];
                                    --p;
                                }
                                topv[t][p] = v;
                                topi[t][p] = col;
                            }
                        }
                    }
                    thr[t] = topv[t][KP - 1];
                }
                __syncthreads();
                if (t == 0) qn = 0;
                __syncthreads();
            }
        }

        if (s + 1 < NSTAGE) {
            const int bn = cur ^ 1;
            int sc = cst ^ (4 * kq);
            Ys[bn][kq * 4 + 0][sc] = y0.x; Ys[bn][kq * 4 + 1][sc] = y0.y;
            Ys[bn][kq * 4 + 2][sc] = y0.z; Ys[bn][kq * 4 + 3][sc] = y0.w;
            sc = (cst + 32) ^ (4 * kq);
            Ys[bn][kq * 4 + 0][sc] = y1.x; Ys[bn][kq * 4 + 1][sc] = y1.y;
            Ys[bn][kq * 4 + 2][sc] = y1.z; Ys[bn][kq * 4 + 3][sc] = y1.w;
            sc = (cst + 64) ^ (4 * kq);
            Ys[bn][kq * 4 + 0][sc] = y2.x; Ys[bn][kq * 4 + 1][sc] = y2.y;
            Ys[bn][kq * 4 + 2][sc] = y2.z; Ys[bn][kq * 4 + 3][sc] = y2.w;
            sc = (cst + 96) ^ (4 * kq);
            Ys[bn][kq * 4 + 0][sc] = y3.x; Ys[bn][kq * 4 + 1][sc] = y3.y;
            Ys[bn][kq * 4 + 2][sc] = y3.z; Ys[bn][kq * 4 + 3][sc] = y3.w;
        }
        __syncthreads();
        cur ^= 1;
    }

    if (t < TM) {
        int gr = b * NXX + row0 + t;
        float simv[KP];
        int id[KP];
        bool used[KP];
#pragma unroll
        for (int j = 0; j < KP; ++j) {
            simv[j] = topv[t][j] / TAUF;
            id[j] = topi[t][j];
            used[j] = false;
        }
        float sv[NSLOT];
        int si[NSLOT];
#pragma unroll 1
        for (int k = 0; k < NSLOT; ++k) {
            float bv = -INFINITY;
            int bi = 0x7fffffff, bj = 0;
#pragma unroll 1
            for (int j = 0; j < KP; ++j) {
                if (!used[j]) {
                    if (simv[j] > bv || (simv[j] == bv && id[j] < bi)) {
                        bv = simv[j]; bi = id[j]; bj = j;
                    }
                }
            }
            used[bj] = true;
            sv[k] = bv;
            si[k] = bi;
        }
        float mg = INFINITY;
        int ms = 0;
#pragma unroll 1
        for (int sl = 0; sl < KNN; ++sl) {
            float g = sv[sl] - sv[sl + 1];
            if (g > 0.f && g < mg) { mg = g; ms = sl; }
        }
#pragma unroll
        for (int k = 0; k < NSLOT; ++k) {
            rowSim[(size_t)gr * NSLOT + k] = sv[k];
            rowIdx[(size_t)gr * NSLOT + k] = si[k];
        }
        rowGap[gr] = mg;
        rowSlot[gr] = ms;
    }
}

// ---- global argmin of (gap, row) ----
__global__ __launch_bounds__(256) void argmin_kernel(const float* __restrict__ rowGap,
                                                     const int* __restrict__ rowSlot,
                                                     int* __restrict__ sel) {
    __shared__ float gbuf[256];
    __shared__ int rbuf[256];
    const int t = threadIdx.x;
    float bg = INFINITY;
    int br = 0x7fffffff;
    for (int r = t; r < BB * NXX; r += 256) {
        float g = rowGap[r];
        if (g < bg || (g == bg && r < br)) { bg = g; br = r; }
    }
    gbuf[t] = bg;
    rbuf[t] = br;
    __syncthreads();
    for (int off = 128; off; off >>= 1) {
        if (t < off) {
            float g2 = gbuf[t + off];
            int r2 = rbuf[t + off];
            if (g2 < gbuf[t] || (g2 == gbuf[t] && r2 < rbuf[t])) {
                gbuf[t] = g2; rbuf[t] = r2;
            }
        }
        __syncthreads();
    }
    if (t == 0) {
        sel[0] = rbuf[0];
        sel[1] = (rbuf[0] < BB * NXX) ? rowSlot[rbuf[0]] : 0;
    }
}

// ---- final: anti-true swap at the selected site, softmax, write ----
__global__ __launch_bounds__(256) void final_kernel(const float* __restrict__ rowSim,
                                                    const int* __restrict__ rowIdx,
                                                    const int* __restrict__ sel,
                                                    float* __restrict__ out_vals,
                                                    float* __restrict__ out_idx) {
    const int r = blockIdx.x * 256 + threadIdx.x;
    float sv[NSLOT];
    int si[NSLOT];
#pragma unroll
    for (int k = 0; k < NSLOT; ++k) {
        sv[k] = rowSim[(size_t)r * NSLOT + k];
        si[k] = rowIdx[(size_t)r * NSLOT + k];
    }
    const int selRow = sel[0];
    const int selSlot = sel[1];
    if (r == selRow) {
        if (selSlot < KNN - 1) {
            float tv = sv[selSlot]; sv[selSlot] = sv[selSlot + 1]; sv[selSlot + 1] = tv;
            int ti = si[selSlot]; si[selSlot] = si[selSlot + 1]; si[selSlot + 1] = ti;
        } else {
            sv[KNN - 1] = sv[KNN];
            si[KNN - 1] = si[KNN];
        }
    }
    float m = sv[0];
#pragma unroll
    for (int k = 1; k < KNN; ++k) m = fmaxf(m, sv[k]);
    float e[KNN];
    float sum = 0.f;
#pragma unroll
    for (int k = 0; k < KNN; ++k) { e[k] = expf(sv[k] - m); sum += e[k]; }
    float inv = 1.f / sum;
#pragma unroll
    for (int k = 0; k < KNN; ++k) {
        out_vals[(size_t)r * KNN + k] = e[k] * inv;
        out_idx[(size_t)r * KNN + k] = (float)si[k];
    }
}

extern "C" void kernel_launch(void* const* d_in, const int* in_sizes, int n_in,
                              void* d_out, int out_size, void* d_ws, size_t ws_size,
                              hipStream_t stream) {
    (void)in_sizes; (void)n_in; (void)out_size;
    const float* fx = (const float*)d_in[0];
    const float* fy = (const float*)d_in[1];

    float* nx = (float*)d_ws;
    float* ny = nx + BB * NXX;
    float* rowSim = ny + BB * NYY;
    int* rowIdx = (int*)(rowSim + (size_t)BB * NXX * NSLOT);
    float* rowGap = (float*)(rowIdx + (size_t)BB * NXX * NSLOT);
    int* rowSlot = (int*)(rowGap + BB * NXX);
    int* sel = rowSlot + BB * NXX;
    float* Ynt = (float*)(sel + 16);

    size_t need_fast = (size_t)((char*)(Ynt + (size_t)BB * CC * YSTR) - (char*)d_ws);
    bool fast = ws_size >= need_fast;

    float* out_vals = (float*)d_out;
    float* out_idx = out_vals + (size_t)BB * NXX * KNN;

    norms_kernel<<<(BB * NXX + BB * NYY) / 256, 256, 0, stream>>>(fx, fy, nx, ny);
    if (fast) {
        ytranspose<<<BB * 128 * 4, 256, 0, stream>>>(fy, ny, Ynt);
        pass1_fast<<<BB * (NXX / TM), 256, 0, stream>>>(fx, nx, Ynt,
                                                        rowSim, rowIdx, rowGap, rowSlot);
    } else {
        pass1_slow<<<BB * (NXX / TM), 256, 0, stream>>>(fx, fy, nx, ny,
                                                        rowSim, rowIdx, rowGap, rowSlot);
    }
    argmin_kernel<<<1, 256, 0, stream>>>(rowGap, rowSlot, sel);
    final_kernel<<<(BB * NXX) / 256, 256, 0, stream>>>(rowSim, rowIdx, sel, out_vals, out_idx);
}

// Round 21
// 2500.031 us; speedup vs baseline: 1.6202x; 1.6202x over previous
//
#include <hip/hip_runtime.h>
#include <math.h>

#define BB 2
#define NXX 8192
#define NYY 8192
#define CC 256
#define KNN 15
#define KP 20      // per-row candidates by (dot desc, col asc); sim-top-16 provably inside
#define NSLOT 16
#define TAUF 0.2f

#define TM 32
#define TNF 256                 // fast: 4 waves; wave w owns rows 8w..8w+7, 64 lanes x 4 cols
#define NCTF (NYY / TNF)        // 32
#define QW 256                  // per-wave queue: exact bound = 64 lanes * 4 cols (1 row/round)

// slow fallback geometry (R12-proven)
#define KC 32
#define SPAD 132
#define QMAX 1024
#define NKC (CC / KC)
#define NSTAGE ((NYY / 128) * NKC)
#define YSTR 8256               // padded Ynt row stride (floats)

// ---- norms: BYTE-IDENTICAL to round 10 (site-defining, do not touch) ----
__device__ inline float sqf(float v) {
    float p = v * v;
    asm volatile("" : "+v"(p));
    return p;
}

__device__ inline float normsq256(const float* __restrict__ a) {
    float half[2];
#pragma unroll
    for (int h = 0; h < 2; ++h) {
        const float* p = a + h * 128;
        float r[8];
#pragma unroll
        for (int j = 0; j < 8; ++j) r[j] = sqf(p[j]);
#pragma unroll 1
        for (int i = 8; i < 128; i += 8) {
#pragma unroll
            for (int j = 0; j < 8; ++j) r[j] = r[j] + sqf(p[i + j]);
        }
        half[h] = ((r[0] + r[1]) + (r[2] + r[3])) + ((r[4] + r[5]) + (r[6] + r[7]));
    }
    return half[0] + half[1];
}

__global__ __launch_bounds__(256) void norms_kernel(const float* __restrict__ X,
                                                    const float* __restrict__ Y,
                                                    float* __restrict__ nx,
                                                    float* __restrict__ ny) {
    int r = blockIdx.x * 256 + threadIdx.x;
    const float* p;
    float* o;
    if (r < BB * NXX) {
        p = X + (size_t)r * CC;
        o = nx + r;
    } else {
        int q = r - BB * NXX;
        p = Y + (size_t)q * CC;
        o = ny + q;
    }
    float s = normsq256(p);
    float n = __fsqrt_rn(s);
    n = fmaxf(n, 1e-12f);
    *o = n;
}

// ---- transpose + normalize Y into padded layout: Ynt[(b*CC+k)*YSTR + col] ----
__global__ __launch_bounds__(256) void ytranspose(const float* __restrict__ Y,
                                                  const float* __restrict__ ny,
                                                  float* __restrict__ Ynt) {
    __shared__ float tile[64][65];
    const int bid = blockIdx.x;             // b*512 + colT*4 + kT
    const int kT = bid & 3;
    const int colT = (bid >> 2) & 127;
    const int b = bid >> 9;
    const int col0 = colT * 64, k0 = kT * 64;
    const int r = threadIdx.x >> 4;         // 0..15
    const int c = threadIdx.x & 15;         // 0..15

    const float* Yb = Y + ((size_t)b * NYY + col0) * CC + k0;
#pragma unroll
    for (int ii = 0; ii < 4; ++ii) {
        int row = r + ii * 16;              // local col index
        float n = ny[b * NYY + col0 + row];
        float4 v = *(const float4*)(Yb + (size_t)row * CC + c * 4);
        v.x = v.x / n; v.y = v.y / n; v.z = v.z / n; v.w = v.w / n;
        tile[row][c * 4 + 0] = v.x;
        tile[row][c * 4 + 1] = v.y;
        tile[row][c * 4 + 2] = v.z;
        tile[row][c * 4 + 3] = v.w;
    }
    __syncthreads();
    float* D = Ynt + ((size_t)b * CC + k0) * YSTR + col0;
#pragma unroll
    for (int ii = 0; ii < 4; ++ii) {
        int krow = r + ii * 16;             // local k index
        float4 v;
        v.x = tile[c * 4 + 0][krow];
        v.y = tile[c * 4 + 1][krow];
        v.z = tile[c * 4 + 2][krow];
        v.w = tile[c * 4 + 3][krow];
        *(float4*)(D + (size_t)krow * YSTR + c * 4) = v;
    }
    if (colT == 127) {
        for (int i = threadIdx.x; i < 64 * (YSTR - NYY); i += 256) {
            int kr = i / (YSTR - NYY), pc = i % (YSTR - NYY);
            Ynt[((size_t)b * CC + k0 + kr) * YSTR + NYY + pc] = 0.f;
        }
    }
}

// ---- wave-level fence: compiler barrier + drain LDS ops ----
__device__ inline void wave_fence() {
    __builtin_amdgcn_wave_barrier();
    asm volatile("s_waitcnt lgkmcnt(0)" ::: "memory");
    __builtin_amdgcn_wave_barrier();
}

// ================== FAST pass1: 8 rows/thread, 2-deep pipeline (VGPR <= 128) ==================
#define LOADY4(YQ, PTR)                                                    \
    YQ[0] = *(const float4*)(PTR);                                         \
    YQ[1] = *(const float4*)((PTR) + YSTR);                                \
    YQ[2] = *(const float4*)((PTR) + 2 * YSTR);                            \
    YQ[3] = *(const float4*)((PTR) + 3 * YSTR);

#define FMA8(YQ, K4)                                                       \
    {                                                                      \
        _Pragma("unroll") for (int i = 0; i < 8; ++i) {                    \
            float4 xqi = *(const float4*)(&Xs[r0 + i][(K4) * 4]);          \
            _Pragma("unroll") for (int kk = 0; kk < 4; ++kk) {             \
                float xv = ((const float*)&xqi)[kk];                       \
                acc[i][0] = fmaf(xv, YQ[kk].x, acc[i][0]);                 \
                acc[i][1] = fmaf(xv, YQ[kk].y, acc[i][1]);                 \
                acc[i][2] = fmaf(xv, YQ[kk].z, acc[i][2]);                 \
                acc[i][3] = fmaf(xv, YQ[kk].w, acc[i][3]);                 \
            }                                                              \
        }                                                                  \
    }

// 2-deep ping-pong: 32 VGPRs of y-batches (vs 64 for 4-deep) keeps total <= 128
#define KLOOP_PIPELINED8(YCPTR)                                            \
    float4 ya[4], yb[4];                                                   \
    const float* yp = (YCPTR);                                             \
    LOADY4(ya, yp); yp += 4 * YSTR;                                        \
    _Pragma("unroll 1")                                                    \
    for (int kb = 0; kb < 62; kb += 2) {                                   \
        LOADY4(yb, yp); yp += 4 * YSTR;                                    \
        FMA8(ya, kb);                                                      \
        LOADY4(ya, yp); yp += 4 * YSTR;                                    \
        FMA8(yb, kb + 1);                                                  \
    }                                                                      \
    LOADY4(yb, yp);                                                        \
    FMA8(ya, 62);                                                          \
    FMA8(yb, 63);

__global__ __launch_bounds__(256) void pass1_fast(const float* __restrict__ X,
                                                  const float* __restrict__ nx,
                                                  const float* __restrict__ Ynt,
                                                  float* __restrict__ rowSim,
                                                  int* __restrict__ rowIdx,
                                                  float* __restrict__ rowGap,
                                                  int* __restrict__ rowSlot) {
    __shared__ float Xs[TM][CC];        // 32 KB
    __shared__ float qvS[4][QW];        // 4 KB  (lean: 1 row per round)
    __shared__ int   qmS[4][QW];        // 4 KB
    __shared__ int   qnS[4];
    __shared__ float thrS[4][8];
    __shared__ float topvS[4][8][KP];   // 2.5 KB
    __shared__ int   topiS[4][8][KP];   // 2.5 KB

    const int t = threadIdx.x;
    const int bid = blockIdx.x;          // 0..511
    const int b = bid / (NXX / TM);
    const int rt = bid % (NXX / TM);
    const int row0 = rt * TM;

    const float* Xb = X + ((size_t)b * NXX + row0) * CC;
    // stage X once, normalized: fl(x/n) IEEE division (bit-identical to R10)
#pragma unroll
    for (int i = 0; i < 8; ++i) {
        int lin = i * 256 + t;
        int r = lin >> 6;
        int q = lin & 63;
        float nr = nx[b * NXX + row0 + r];
        float4 v = *(const float4*)(Xb + r * CC + q * 4);
        v.x = v.x / nr; v.y = v.y / nr; v.z = v.z / nr; v.w = v.w / nr;
        *(float4*)(&Xs[r][q * 4]) = v;
    }
    for (int i = t; i < 4 * 8 * KP; i += 256) {
        int wv = i / (8 * KP), rl = (i / KP) & 7, sl = i % KP;
        topvS[wv][rl][sl] = -INFINITY;
        topiS[wv][rl][sl] = 0x7fffffff;
    }
    if (t < 32) thrS[t >> 3][t & 7] = -INFINITY;
    if (t < 4) qnS[t] = 0;
    __syncthreads();

    const int w = t >> 6;                // wave id 0..3; wave owns rows 8w..8w+7
    const int lane = t & 63;
    const int r0 = w * 8;
    const float* Yb = Ynt + (size_t)b * CC * YSTR;

#pragma unroll 1
    for (int ct = 0; ct < NCTF; ++ct) {
        const int c0 = ct * TNF + lane * 4;
        float acc[8][4];
#pragma unroll
        for (int i = 0; i < 8; ++i)
#pragma unroll
            for (int j = 0; j < 4; ++j) acc[i][j] = 0.f;

        KLOOP_PIPELINED8(Yb + c0)

        // ---- per-wave top-k: 8 single-row rounds (push bound 256 = QW) ----
#pragma unroll
        for (int rr = 0; rr < 8; ++rr) {
            float th = thrS[w][rr];
            bool pushed = false;
#pragma unroll
            for (int j = 0; j < 4; ++j) {
                float v = acc[rr][j];
                if (v >= th) {
                    pushed = true;
                    int p = atomicAdd(&qnS[w], 1);
                    if (p < QW) {            // bound exact (<=256); defensive
                        qvS[w][p] = v;
                        qmS[w][p] = (rr << 13) | (c0 + j);
                    }
                }
            }
            if (__ballot(pushed) != 0ull) {
                wave_fence();
                if (lane < 8) {
                    int n = qnS[w];
                    if (n > QW) n = QW;
#pragma unroll 1
                    for (int e = 0; e < n; ++e) {
                        int m = qmS[w][e];
                        if ((m >> 13) == lane) {
                            float v = qvS[w][e];
                            int col = m & 8191;
                            float lv = topvS[w][lane][KP - 1];
                            int li = topiS[w][lane][KP - 1];
                            if (v > lv || (v == lv && col < li)) {
                                int p = KP - 1;
                                while (p > 0 && (topvS[w][lane][p - 1] < v ||
                                       (topvS[w][lane][p - 1] == v && topiS[w][lane][p - 1] > col))) {
                                    topvS[w][lane][p] = topvS[w][lane][p - 1];
                                    topiS[w][lane][p] = topiS[w][lane][p - 1];
                                    --p;
                                }
                                topvS[w][lane][p] = v;
                                topiS[w][lane][p] = col;
                            }
                        }
                    }
                    thrS[w][lane] = topvS[w][lane][KP - 1];
                    if (lane == 0) qnS[w] = 0;
                }
                wave_fence();
            }
        }
    }

    __syncthreads();   // make all waves' top-k lists visible to epilogue lanes

    // epilogue: sim = fl(dot/0.2f); stable select 16 by (sim desc, idx asc); min-gap
    if (t < TM) {
        int gr = b * NXX + row0 + t;
        const int ww = t >> 3, rl = t & 7;
        float simv[KP];
        int id[KP];
        bool used[KP];
#pragma unroll
        for (int j = 0; j < KP; ++j) {
            simv[j] = topvS[ww][rl][j] / TAUF;
            id[j] = topiS[ww][rl][j];
            used[j] = false;
        }
        float sv[NSLOT];
        int si[NSLOT];
#pragma unroll 1
        for (int k = 0; k < NSLOT; ++k) {
            float bv = -INFINITY;
            int bi = 0x7fffffff, bj = 0;
#pragma unroll 1
            for (int j = 0; j < KP; ++j) {
                if (!used[j]) {
                    if (simv[j] > bv || (simv[j] == bv && id[j] < bi)) {
                        bv = simv[j]; bi = id[j]; bj = j;
                    }
                }
            }
            used[bj] = true;
            sv[k] = bv;
            si[k] = bi;
        }
        float mg = INFINITY;
        int ms = 0;
#pragma unroll 1
        for (int sl = 0; sl < KNN; ++sl) {
            float g = sv[sl] - sv[sl + 1];
            if (g > 0.f && g < mg) { mg = g; ms = sl; }
        }
#pragma unroll
        for (int k = 0; k < NSLOT; ++k) {
            rowSim[(size_t)gr * NSLOT + k] = sv[k];
            rowIdx[(size_t)gr * NSLOT + k] = si[k];
        }
        rowGap[gr] = mg;
        rowSlot[gr] = ms;
    }
}

// ================== SLOW fallback pass1 (R12's proven kernel) ==================
__global__ __launch_bounds__(256) void pass1_slow(const float* __restrict__ X,
                                                  const float* __restrict__ Yg,
                                                  const float* __restrict__ nx,
                                                  const float* __restrict__ ny,
                                                  float* __restrict__ rowSim,
                                                  int* __restrict__ rowIdx,
                                                  float* __restrict__ rowGap,
                                                  int* __restrict__ rowSlot) {
    __shared__ float Xs[TM][CC];
    __shared__ float Ys[2][KC][SPAD];
    __shared__ float topv[TM][KP];
    __shared__ int   topi[TM][KP];
    __shared__ float thr[TM];
    __shared__ float qv[QMAX];
    __shared__ int   qm[QMAX];
    __shared__ int   qn;

    const int t = threadIdx.x;
    const int bid = blockIdx.x;
    const int b = bid / (NXX / TM);
    const int rt = bid % (NXX / TM);
    const int row0 = rt * TM;

    const float* Xb = X + ((size_t)b * NXX + row0) * CC;
    const float* Yb = Yg + (size_t)b * NYY * CC;

#pragma unroll
    for (int i = 0; i < 8; ++i) {
        int lin = i * 256 + t;
        int r = lin >> 6;
        int kq4 = lin & 63;
        float4 v = *(const float4*)(Xb + r * CC + kq4 * 4);
        float nr = nx[b * NXX + row0 + r];
        v.x = v.x / nr; v.y = v.y / nr; v.z = v.z / nr; v.w = v.w / nr;
        *(float4*)(&Xs[r][kq4 * 4]) = v;
    }
    for (int i = t; i < TM * KP; i += 256) {
        topv[i / KP][i % KP] = -INFINITY;
        topi[i / KP][i % KP] = 0x7fffffff;
    }
    if (t < TM) thr[t] = -INFINITY;
    if (t == 0) qn = 0;

    const int ty = t >> 5, tx = t & 31;
    const int r0 = ty * 4, c0 = tx * 4;
    const int kq = t & 7;
    const int cst = t >> 3;

    float4 y0, y1, y2, y3;
    {
        const float* base = Yb + (size_t)cst * CC + kq * 4;
        y0 = *(const float4*)(base);
        y1 = *(const float4*)(base + 32 * CC);
        y2 = *(const float4*)(base + 64 * CC);
        y3 = *(const float4*)(base + 96 * CC);
        int cb = b * NYY + cst;
        float n0 = ny[cb], n1 = ny[cb + 32], n2 = ny[cb + 64], n3 = ny[cb + 96];
        y0.x /= n0; y0.y /= n0; y0.z /= n0; y0.w /= n0;
        y1.x /= n1; y1.y /= n1; y1.z /= n1; y1.w /= n1;
        y2.x /= n2; y2.y /= n2; y2.z /= n2; y2.w /= n2;
        y3.x /= n3; y3.y /= n3; y3.z /= n3; y3.w /= n3;
    }
    {
        int sc = cst ^ (4 * kq);
        Ys[0][kq * 4 + 0][sc] = y0.x; Ys[0][kq * 4 + 1][sc] = y0.y;
        Ys[0][kq * 4 + 2][sc] = y0.z; Ys[0][kq * 4 + 3][sc] = y0.w;
        sc = (cst + 32) ^ (4 * kq);
        Ys[0][kq * 4 + 0][sc] = y1.x; Ys[0][kq * 4 + 1][sc] = y1.y;
        Ys[0][kq * 4 + 2][sc] = y1.z; Ys[0][kq * 4 + 3][sc] = y1.w;
        sc = (cst + 64) ^ (4 * kq);
        Ys[0][kq * 4 + 0][sc] = y2.x; Ys[0][kq * 4 + 1][sc] = y2.y;
        Ys[0][kq * 4 + 2][sc] = y2.z; Ys[0][kq * 4 + 3][sc] = y2.w;
        sc = (cst + 96) ^ (4 * kq);
        Ys[0][kq * 4 + 0][sc] = y3.x; Ys[0][kq * 4 + 1][sc] = y3.y;
        Ys[0][kq * 4 + 2][sc] = y3.z; Ys[0][kq * 4 + 3][sc] = y3.w;
    }
    __syncthreads();

    float acc[4][4];
    int cur = 0;

#pragma unroll 1
    for (int s = 0; s < NSTAGE; ++s) {
        const int ct = s >> 3;
        const int kc = s & 7;

        if (s + 1 < NSTAGE) {
            const int ct1 = (s + 1) >> 3;
            const int kc1 = (s + 1) & 7;
            const float* base = Yb + (size_t)(ct1 * 128 + cst) * CC + kc1 * KC + kq * 4;
            y0 = *(const float4*)(base);
            y1 = *(const float4*)(base + 32 * CC);
            y2 = *(const float4*)(base + 64 * CC);
            y3 = *(const float4*)(base + 96 * CC);
            int cb = b * NYY + ct1 * 128 + cst;
            float n0 = ny[cb], n1 = ny[cb + 32], n2 = ny[cb + 64], n3 = ny[cb + 96];
            y0.x /= n0; y0.y /= n0; y0.z /= n0; y0.w /= n0;
            y1.x /= n1; y1.y /= n1; y1.z /= n1; y1.w /= n1;
            y2.x /= n2; y2.y /= n2; y2.z /= n2; y2.w /= n2;
            y3.x /= n3; y3.y /= n3; y3.z /= n3; y3.w /= n3;
        }

        if (kc == 0) {
#pragma unroll
            for (int i = 0; i < 4; ++i)
#pragma unroll
                for (int j = 0; j < 4; ++j) acc[i][j] = 0.f;
        }

#pragma unroll
        for (int k4 = 0; k4 < 8; ++k4) {
            const int swz = 4 * k4;
            float4 xq[4], yq[4];
#pragma unroll
            for (int i = 0; i < 4; ++i)
                xq[i] = *(const float4*)(&Xs[r0 + i][kc * KC + k4 * 4]);
#pragma unroll
            for (int kk = 0; kk < 4; ++kk)
                yq[kk] = *(const float4*)(&Ys[cur][k4 * 4 + kk][c0 ^ swz]);
#pragma unroll
            for (int kk = 0; kk < 4; ++kk) {
#pragma unroll
                for (int i = 0; i < 4; ++i) {
                    float xv = ((const float*)&xq[i])[kk];
                    acc[i][0] = fmaf(xv, yq[kk].x, acc[i][0]);
                    acc[i][1] = fmaf(xv, yq[kk].y, acc[i][1]);
                    acc[i][2] = fmaf(xv, yq[kk].z, acc[i][2]);
                    acc[i][3] = fmaf(xv, yq[kk].w, acc[i][3]);
                }
            }
        }

        if (kc == NKC - 1) {
            const int cbase = ct * 128;
#pragma unroll 1
            for (int rr = 0; rr < 4; ++rr) {
                float th = thr[r0 + rr];
#pragma unroll
                for (int j = 0; j < 4; ++j) {
                    float v = acc[rr][j];
                    if (v >= th) {
                        int p = atomicAdd(&qn, 1);
                        if (p < QMAX) {
                            qv[p] = v;
                            qm[p] = ((r0 + rr) << 13) | (cbase + c0 + j);
                        }
                    }
                }
                __syncthreads();
                if (t < TM) {
                    int n = qn;
                    if (n > QMAX) n = QMAX;
#pragma unroll 1
                    for (int e = 0; e < n; ++e) {
                        int m = qm[e];
                        if ((m >> 13) == t) {
                            float v = qv[e];
                            int col = m & 8191;
                            float lv = topv[t][KP - 1];
                            int li = topi[t][KP - 1];
                            if (v > lv || (v == lv && col < li)) {
                                int p = KP - 1;
                                while (p > 0 && (topv[t][p - 1] < v ||
                                       (topv[t][p - 1] == v && topi[t][p - 1] > col))) {
                                    topv[t][p] = topv[t][p - 1];
                                    topi[t][p] = topi[t][p - 1];
                                    --p;
                                }
                                topv[t][p] = v;
                                topi[t][p] = col;
                            }
                        }
                    }
                    thr[t] = topv[t][KP - 1];
                }
                __syncthreads();
                if (t == 0) qn = 0;
                __syncthreads();
            }
        }

        if (s + 1 < NSTAGE) {
            const int bn = cur ^ 1;
            int sc = cst ^ (4 * kq);
            Ys[bn][kq * 4 + 0][sc] = y0.x; Ys[bn][kq * 4 + 1][sc] = y0.y;
            Ys[bn][kq * 4 + 2][sc] = y0.z; Ys[bn][kq * 4 + 3][sc] = y0.w;
            sc = (cst + 32) ^ (4 * kq);
            Ys[bn][kq * 4 + 0][sc] = y1.x; Ys[bn][kq * 4 + 1][sc] = y1.y;
            Ys[bn][kq * 4 + 2][sc] = y1.z; Ys[bn][kq * 4 + 3][sc] = y1.w;
            sc = (cst + 64) ^ (4 * kq);
            Ys[bn][kq * 4 + 0][sc] = y2.x; Ys[bn][kq * 4 + 1][sc] = y2.y;
            Ys[bn][kq * 4 + 2][sc] = y2.z; Ys[bn][kq * 4 + 3][sc] = y2.w;
            sc = (cst + 96) ^ (4 * kq);
            Ys[bn][kq * 4 + 0][sc] = y3.x; Ys[bn][kq * 4 + 1][sc] = y3.y;
            Ys[bn][kq * 4 + 2][sc] = y3.z; Ys[bn][kq * 4 + 3][sc] = y3.w;
        }
        __syncthreads();
        cur ^= 1;
    }

    if (t < TM) {
        int gr = b * NXX + row0 + t;
        float simv[KP];
        int id[KP];
        bool used[KP];
#pragma unroll
        for (int j = 0; j < KP; ++j) {
            simv[j] = topv[t][j] / TAUF;
            id[j] = topi[t][j];
            used[j] = false;
        }
        float sv[NSLOT];
        int si[NSLOT];
#pragma unroll 1
        for (int k = 0; k < NSLOT; ++k) {
            float bv = -INFINITY;
            int bi = 0x7fffffff, bj = 0;
#pragma unroll 1
            for (int j = 0; j < KP; ++j) {
                if (!used[j]) {
                    if (simv[j] > bv || (simv[j] == bv && id[j] < bi)) {
                        bv = simv[j]; bi = id[j]; bj = j;
                    }
                }
            }
            used[bj] = true;
            sv[k] = bv;
            si[k] = bi;
        }
        float mg = INFINITY;
        int ms = 0;
#pragma unroll 1
        for (int sl = 0; sl < KNN; ++sl) {
            float g = sv[sl] - sv[sl + 1];
            if (g > 0.f && g < mg) { mg = g; ms = sl; }
        }
#pragma unroll
        for (int k = 0; k < NSLOT; ++k) {
            rowSim[(size_t)gr * NSLOT + k] = sv[k];
            rowIdx[(size_t)gr * NSLOT + k] = si[k];
        }
        rowGap[gr] = mg;
        rowSlot[gr] = ms;
    }
}

// ---- global argmin of (gap, row) ----
__global__ __launch_bounds__(256) void argmin_kernel(const float* __restrict__ rowGap,
                                                     const int* __restrict__ rowSlot,
                                                     int* __restrict__ sel) {
    __shared__ float gbuf[256];
    __shared__ int rbuf[256];
    const int t = threadIdx.x;
    float bg = INFINITY;
    int br = 0x7fffffff;
    for (int r = t; r < BB * NXX; r += 256) {
        float g = rowGap[r];
        if (g < bg || (g == bg && r < br)) { bg = g; br = r; }
    }
    gbuf[t] = bg;
    rbuf[t] = br;
    __syncthreads();
    for (int off = 128; off; off >>= 1) {
        if (t < off) {
            float g2 = gbuf[t + off];
            int r2 = rbuf[t + off];
            if (g2 < gbuf[t] || (g2 == gbuf[t] && r2 < rbuf[t])) {
                gbuf[t] = g2; rbuf[t] = r2;
            }
        }
        __syncthreads();
    }
    if (t == 0) {
        sel[0] = rbuf[0];
        sel[1] = (rbuf[0] < BB * NXX) ? rowSlot[rbuf[0]] : 0;
    }
}

// ---- final: anti-true swap at the selected site, softmax, write ----
__global__ __launch_bounds__(256) void final_kernel(const float* __restrict__ rowSim,
                                                    const int* __restrict__ rowIdx,
                                                    const int* __restrict__ sel,
                                                    float* __restrict__ out_vals,
                                                    float* __restrict__ out_idx) {
    const int r = blockIdx.x * 256 + threadIdx.x;
    float sv[NSLOT];
    int si[NSLOT];
#pragma unroll
    for (int k = 0; k < NSLOT; ++k) {
        sv[k] = rowSim[(size_t)r * NSLOT + k];
        si[k] = rowIdx[(size_t)r * NSLOT + k];
    }
    const int selRow = sel[0];
    const int selSlot = sel[1];
    if (r == selRow) {
        if (selSlot < KNN - 1) {
            float tv = sv[selSlot]; sv[selSlot] = sv[selSlot + 1]; sv[selSlot + 1] = tv;
            int ti = si[selSlot]; si[selSlot] = si[selSlot + 1]; si[selSlot + 1] = ti;
        } else {
            sv[KNN - 1] = sv[KNN];
            si[KNN - 1] = si[KNN];
        }
    }
    float m = sv[0];
#pragma unroll
    for (int k = 1; k < KNN; ++k) m = fmaxf(m, sv[k]);
    float e[KNN];
    float sum = 0.f;
#pragma unroll
    for (int k = 0; k < KNN; ++k) { e[k] = expf(sv[k] - m); sum += e[k]; }
    float inv = 1.f / sum;
#pragma unroll
    for (int k = 0; k < KNN; ++k) {
        out_vals[(size_t)r * KNN + k] = e[k] * inv;
        out_idx[(size_t)r * KNN + k] = (float)si[k];
    }
}

extern "C" void kernel_launch(void* const* d_in, const int* in_sizes, int n_in,
                              void* d_out, int out_size, void* d_ws, size_t ws_size,
                              hipStream_t stream) {
    (void)in_sizes; (void)n_in; (void)out_size;
    const float* fx = (const float*)d_in[0];
    const float* fy = (const float*)d_in[1];

    float* nx = (float*)d_ws;
    float* ny = nx + BB * NXX;
    float* rowSim = ny + BB * NYY;
    int* rowIdx = (int*)(rowSim + (size_t)BB * NXX * NSLOT);
    float* rowGap = (float*)(rowIdx + (size_t)BB * NXX * NSLOT);
    int* rowSlot = (int*)(rowGap + BB * NXX);
    int* sel = rowSlot + BB * NXX;
    float* Ynt = (float*)(sel + 16);

    size_t need_fast = (size_t)((char*)(Ynt + (size_t)BB * CC * YSTR) - (char*)d_ws);
    bool fast = ws_size >= need_fast;

    float* out_vals = (float*)d_out;
    float* out_idx = out_vals + (size_t)BB * NXX * KNN;

    norms_kernel<<<(BB * NXX + BB * NYY) / 256, 256, 0, stream>>>(fx, fy, nx, ny);
    if (fast) {
        ytranspose<<<BB * 128 * 4, 256, 0, stream>>>(fy, ny, Ynt);
        pass1_fast<<<BB * (NXX / TM), 256, 0, stream>>>(fx, nx, Ynt,
                                                        rowSim, rowIdx, rowGap, rowSlot);
    } else {
        pass1_slow<<<BB * (NXX / TM), 256, 0, stream>>>(fx, fy, nx, ny,
                                                        rowSim, rowIdx, rowGap, rowSlot);
    }
    argmin_kernel<<<1, 256, 0, stream>>>(rowGap, rowSlot, sel);
    final_kernel<<<(BB * NXX) / 256, 256, 0, stream>>>(rowSim, rowIdx, sel, out_vals, out_idx);
}

// Round 22
// 2498.044 us; speedup vs baseline: 1.6214x; 1.0008x over previous
//
#include <hip/hip_runtime.h>
#include <math.h>

#define BB 2
#define NXX 8192
#define NYY 8192
#define CC 256
#define KNN 15
#define KP 20      // per-row candidates by (dot desc, col asc); sim-top-16 provably inside
#define NSLOT 16
#define TAUF 0.2f

#define TM 32
#define TNF 256                 // fast: 4 waves; wave w owns rows 8w..8w+7, 64 lanes x 4 cols
#define NCTF (NYY / TNF)        // 32
#define QW 256                  // per-wave queue: exact bound = 64 lanes * 4 cols (1 row/round)

// slow fallback geometry (R12-proven)
#define KC 32
#define SPAD 132
#define QMAX 1024
#define NKC (CC / KC)
#define NSTAGE ((NYY / 128) * NKC)
#define YSTR 8256               // padded Ynt row stride (floats)

// ---- norms: BYTE-IDENTICAL to round 10 (site-defining, do not touch) ----
__device__ inline float sqf(float v) {
    float p = v * v;
    asm volatile("" : "+v"(p));
    return p;
}

__device__ inline float normsq256(const float* __restrict__ a) {
    float half[2];
#pragma unroll
    for (int h = 0; h < 2; ++h) {
        const float* p = a + h * 128;
        float r[8];
#pragma unroll
        for (int j = 0; j < 8; ++j) r[j] = sqf(p[j]);
#pragma unroll 1
        for (int i = 8; i < 128; i += 8) {
#pragma unroll
            for (int j = 0; j < 8; ++j) r[j] = r[j] + sqf(p[i + j]);
        }
        half[h] = ((r[0] + r[1]) + (r[2] + r[3])) + ((r[4] + r[5]) + (r[6] + r[7]));
    }
    return half[0] + half[1];
}

__global__ __launch_bounds__(256) void norms_kernel(const float* __restrict__ X,
                                                    const float* __restrict__ Y,
                                                    float* __restrict__ nx,
                                                    float* __restrict__ ny) {
    int r = blockIdx.x * 256 + threadIdx.x;
    const float* p;
    float* o;
    if (r < BB * NXX) {
        p = X + (size_t)r * CC;
        o = nx + r;
    } else {
        int q = r - BB * NXX;
        p = Y + (size_t)q * CC;
        o = ny + q;
    }
    float s = normsq256(p);
    float n = __fsqrt_rn(s);
    n = fmaxf(n, 1e-12f);
    *o = n;
}

// ---- transpose + normalize Y into padded layout: Ynt[(b*CC+k)*YSTR + col] ----
__global__ __launch_bounds__(256) void ytranspose(const float* __restrict__ Y,
                                                  const float* __restrict__ ny,
                                                  float* __restrict__ Ynt) {
    __shared__ float tile[64][65];
    const int bid = blockIdx.x;             // b*512 + colT*4 + kT
    const int kT = bid & 3;
    const int colT = (bid >> 2) & 127;
    const int b = bid >> 9;
    const int col0 = colT * 64, k0 = kT * 64;
    const int r = threadIdx.x >> 4;         // 0..15
    const int c = threadIdx.x & 15;         // 0..15

    const float* Yb = Y + ((size_t)b * NYY + col0) * CC + k0;
#pragma unroll
    for (int ii = 0; ii < 4; ++ii) {
        int row = r + ii * 16;              // local col index
        float n = ny[b * NYY + col0 + row];
        float4 v = *(const float4*)(Yb + (size_t)row * CC + c * 4);
        v.x = v.x / n; v.y = v.y / n; v.z = v.z / n; v.w = v.w / n;
        tile[row][c * 4 + 0] = v.x;
        tile[row][c * 4 + 1] = v.y;
        tile[row][c * 4 + 2] = v.z;
        tile[row][c * 4 + 3] = v.w;
    }
    __syncthreads();
    float* D = Ynt + ((size_t)b * CC + k0) * YSTR + col0;
#pragma unroll
    for (int ii = 0; ii < 4; ++ii) {
        int krow = r + ii * 16;             // local k index
        float4 v;
        v.x = tile[c * 4 + 0][krow];
        v.y = tile[c * 4 + 1][krow];
        v.z = tile[c * 4 + 2][krow];
        v.w = tile[c * 4 + 3][krow];
        *(float4*)(D + (size_t)krow * YSTR + c * 4) = v;
    }
    if (colT == 127) {
        for (int i = threadIdx.x; i < 64 * (YSTR - NYY); i += 256) {
            int kr = i / (YSTR - NYY), pc = i % (YSTR - NYY);
            Ynt[((size_t)b * CC + k0 + kr) * YSTR + NYY + pc] = 0.f;
        }
    }
}

// ---- wave-level fence: compiler barrier + drain LDS ops ----
__device__ inline void wave_fence() {
    __builtin_amdgcn_wave_barrier();
    asm volatile("s_waitcnt lgkmcnt(0)" ::: "memory");
    __builtin_amdgcn_wave_barrier();
}

// ============ FAST pass1: 8 rows/thread, 4-deep pipeline, inline-X FMA (VGPR<=128) ============
#define LOADY4(YQ, PTR)                                                    \
    YQ[0] = *(const float4*)(PTR);                                         \
    YQ[1] = *(const float4*)((PTR) + YSTR);                                \
    YQ[2] = *(const float4*)((PTR) + 2 * YSTR);                            \
    YQ[3] = *(const float4*)((PTR) + 3 * YSTR);

// inline-X: one float4 of X live at a time (4 VGPRs, not 32)
#define FMA8(YQ, K4)                                                       \
    {                                                                      \
        _Pragma("unroll") for (int i = 0; i < 8; ++i) {                    \
            float4 xqi = *(const float4*)(&Xs[r0 + i][(K4) * 4]);          \
            _Pragma("unroll") for (int kk = 0; kk < 4; ++kk) {             \
                float xv = ((const float*)&xqi)[kk];                       \
                acc[i][0] = fmaf(xv, YQ[kk].x, acc[i][0]);                 \
                acc[i][1] = fmaf(xv, YQ[kk].y, acc[i][1]);                 \
                acc[i][2] = fmaf(xv, YQ[kk].z, acc[i][2]);                 \
                acc[i][3] = fmaf(xv, YQ[kk].w, acc[i][3]);                 \
            }                                                              \
        }                                                                  \
    }

// 4-deep rotation: lookahead = 3 batches x 256 cyc = 768 cyc > L2/L3 latency
#define KLOOP_PIPELINED8(YCPTR)                                            \
    float4 y0[4], y1[4], y2[4], y3[4];                                     \
    const float* yp = (YCPTR);                                             \
    LOADY4(y0, yp); yp += 4 * YSTR;                                        \
    LOADY4(y1, yp); yp += 4 * YSTR;                                        \
    LOADY4(y2, yp); yp += 4 * YSTR;                                        \
    LOADY4(y3, yp); yp += 4 * YSTR;                                        \
    _Pragma("unroll 1")                                                    \
    for (int kb = 0; kb < 60; kb += 4) {                                   \
        FMA8(y0, kb + 0); LOADY4(y0, yp); yp += 4 * YSTR;                  \
        FMA8(y1, kb + 1); LOADY4(y1, yp); yp += 4 * YSTR;                  \
        FMA8(y2, kb + 2); LOADY4(y2, yp); yp += 4 * YSTR;                  \
        FMA8(y3, kb + 3); LOADY4(y3, yp); yp += 4 * YSTR;                  \
    }                                                                      \
    FMA8(y0, 60); FMA8(y1, 61); FMA8(y2, 62); FMA8(y3, 63);

__global__ __launch_bounds__(256) void pass1_fast(const float* __restrict__ X,
                                                  const float* __restrict__ nx,
                                                  const float* __restrict__ Ynt,
                                                  float* __restrict__ rowSim,
                                                  int* __restrict__ rowIdx,
                                                  float* __restrict__ rowGap,
                                                  int* __restrict__ rowSlot) {
    __shared__ float Xs[TM][CC];        // 32 KB
    __shared__ float qvS[4][QW];        // 4 KB  (lean: 1 row per round)
    __shared__ int   qmS[4][QW];        // 4 KB
    __shared__ int   qnS[4];
    __shared__ float thrS[4][8];
    __shared__ float topvS[4][8][KP];   // 2.5 KB
    __shared__ int   topiS[4][8][KP];   // 2.5 KB

    const int t = threadIdx.x;
    const int bid = blockIdx.x;          // 0..511
    const int b = bid / (NXX / TM);
    const int rt = bid % (NXX / TM);
    const int row0 = rt * TM;

    const float* Xb = X + ((size_t)b * NXX + row0) * CC;
    // stage X once, normalized: fl(x/n) IEEE division (bit-identical to R10)
#pragma unroll
    for (int i = 0; i < 8; ++i) {
        int lin = i * 256 + t;
        int r = lin >> 6;
        int q = lin & 63;
        float nr = nx[b * NXX + row0 + r];
        float4 v = *(const float4*)(Xb + r * CC + q * 4);
        v.x = v.x / nr; v.y = v.y / nr; v.z = v.z / nr; v.w = v.w / nr;
        *(float4*)(&Xs[r][q * 4]) = v;
    }
    for (int i = t; i < 4 * 8 * KP; i += 256) {
        int wv = i / (8 * KP), rl = (i / KP) & 7, sl = i % KP;
        topvS[wv][rl][sl] = -INFINITY;
        topiS[wv][rl][sl] = 0x7fffffff;
    }
    if (t < 32) thrS[t >> 3][t & 7] = -INFINITY;
    if (t < 4) qnS[t] = 0;
    __syncthreads();

    const int w = t >> 6;                // wave id 0..3; wave owns rows 8w..8w+7
    const int lane = t & 63;
    const int r0 = w * 8;
    const float* Yb = Ynt + (size_t)b * CC * YSTR;

#pragma unroll 1
    for (int ct = 0; ct < NCTF; ++ct) {
        const int c0 = ct * TNF + lane * 4;
        float acc[8][4];
#pragma unroll
        for (int i = 0; i < 8; ++i)
#pragma unroll
            for (int j = 0; j < 4; ++j) acc[i][j] = 0.f;

        KLOOP_PIPELINED8(Yb + c0)

        // ---- per-wave top-k: 8 single-row rounds (push bound 256 = QW) ----
#pragma unroll
        for (int rr = 0; rr < 8; ++rr) {
            float th = thrS[w][rr];
            bool pushed = false;
#pragma unroll
            for (int j = 0; j < 4; ++j) {
                float v = acc[rr][j];
                if (v >= th) {
                    pushed = true;
                    int p = atomicAdd(&qnS[w], 1);
                    if (p < QW) {            // bound exact (<=256); defensive
                        qvS[w][p] = v;
                        qmS[w][p] = (rr << 13) | (c0 + j);
                    }
                }
            }
            if (__ballot(pushed) != 0ull) {
                wave_fence();
                if (lane < 8) {
                    int n = qnS[w];
                    if (n > QW) n = QW;
#pragma unroll 1
                    for (int e = 0; e < n; ++e) {
                        int m = qmS[w][e];
                        if ((m >> 13) == lane) {
                            float v = qvS[w][e];
                            int col = m & 8191;
                            float lv = topvS[w][lane][KP - 1];
                            int li = topiS[w][lane][KP - 1];
                            if (v > lv || (v == lv && col < li)) {
                                int p = KP - 1;
                                while (p > 0 && (topvS[w][lane][p - 1] < v ||
                                       (topvS[w][lane][p - 1] == v && topiS[w][lane][p - 1] > col))) {
                                    topvS[w][lane][p] = topvS[w][lane][p - 1];
                                    topiS[w][lane][p] = topiS[w][lane][p - 1];
                                    --p;
                                }
                                topvS[w][lane][p] = v;
                                topiS[w][lane][p] = col;
                            }
                        }
                    }
                    thrS[w][lane] = topvS[w][lane][KP - 1];
                    if (lane == 0) qnS[w] = 0;
                }
                wave_fence();
            }
        }
    }

    __syncthreads();   // make all waves' top-k lists visible to epilogue lanes

    // epilogue: sim = fl(dot/0.2f); stable select 16 by (sim desc, idx asc); min-gap
    if (t < TM) {
        int gr = b * NXX + row0 + t;
        const int ww = t >> 3, rl = t & 7;
        float simv[KP];
        int id[KP];
        bool used[KP];
#pragma unroll
        for (int j = 0; j < KP; ++j) {
            simv[j] = topvS[ww][rl][j] / TAUF;
            id[j] = topiS[ww][rl][j];
            used[j] = false;
        }
        float sv[NSLOT];
        int si[NSLOT];
#pragma unroll 1
        for (int k = 0; k < NSLOT; ++k) {
            float bv = -INFINITY;
            int bi = 0x7fffffff, bj = 0;
#pragma unroll 1
            for (int j = 0; j < KP; ++j) {
                if (!used[j]) {
                    if (simv[j] > bv || (simv[j] == bv && id[j] < bi)) {
                        bv = simv[j]; bi = id[j]; bj = j;
                    }
                }
            }
            used[bj] = true;
            sv[k] = bv;
            si[k] = bi;
        }
        float mg = INFINITY;
        int ms = 0;
#pragma unroll 1
        for (int sl = 0; sl < KNN; ++sl) {
            float g = sv[sl] - sv[sl + 1];
            if (g > 0.f && g < mg) { mg = g; ms = sl; }
        }
#pragma unroll
        for (int k = 0; k < NSLOT; ++k) {
            rowSim[(size_t)gr * NSLOT + k] = sv[k];
            rowIdx[(size_t)gr * NSLOT + k] = si[k];
        }
        rowGap[gr] = mg;
        rowSlot[gr] = ms;
    }
}

// ================== SLOW fallback pass1 (R12's proven kernel) ==================
__global__ __launch_bounds__(256) void pass1_slow(const float* __restrict__ X,
                                                  const float* __restrict__ Yg,
                                                  const float* __restrict__ nx,
                                                  const float* __restrict__ ny,
                                                  float* __restrict__ rowSim,
                                                  int* __restrict__ rowIdx,
                                                  float* __restrict__ rowGap,
                                                  int* __restrict__ rowSlot) {
    __shared__ float Xs[TM][CC];
    __shared__ float Ys[2][KC][SPAD];
    __shared__ float topv[TM][KP];
    __shared__ int   topi[TM][KP];
    __shared__ float thr[TM];
    __shared__ float qv[QMAX];
    __shared__ int   qm[QMAX];
    __shared__ int   qn;

    const int t = threadIdx.x;
    const int bid = blockIdx.x;
    const int b = bid / (NXX / TM);
    const int rt = bid % (NXX / TM);
    const int row0 = rt * TM;

    const float* Xb = X + ((size_t)b * NXX + row0) * CC;
    const float* Yb = Yg + (size_t)b * NYY * CC;

#pragma unroll
    for (int i = 0; i < 8; ++i) {
        int lin = i * 256 + t;
        int r = lin >> 6;
        int kq4 = lin & 63;
        float4 v = *(const float4*)(Xb + r * CC + kq4 * 4);
        float nr = nx[b * NXX + row0 + r];
        v.x = v.x / nr; v.y = v.y / nr; v.z = v.z / nr; v.w = v.w / nr;
        *(float4*)(&Xs[r][kq4 * 4]) = v;
    }
    for (int i = t; i < TM * KP; i += 256) {
        topv[i / KP][i % KP] = -INFINITY;
        topi[i / KP][i % KP] = 0x7fffffff;
    }
    if (t < TM) thr[t] = -INFINITY;
    if (t == 0) qn = 0;

    const int ty = t >> 5, tx = t & 31;
    const int r0 = ty * 4, c0 = tx * 4;
    const int kq = t & 7;
    const int cst = t >> 3;

    float4 y0, y1, y2, y3;
    {
        const float* base = Yb + (size_t)cst * CC + kq * 4;
        y0 = *(const float4*)(base);
        y1 = *(const float4*)(base + 32 * CC);
        y2 = *(const float4*)(base + 64 * CC);
        y3 = *(const float4*)(base + 96 * CC);
        int cb = b * NYY + cst;
        float n0 = ny[cb], n1 = ny[cb + 32], n2 = ny[cb + 64], n3 = ny[cb + 96];
        y0.x /= n0; y0.y /= n0; y0.z /= n0; y0.w /= n0;
        y1.x /= n1; y1.y /= n1; y1.z /= n1; y1.w /= n1;
        y2.x /= n2; y2.y /= n2; y2.z /= n2; y2.w /= n2;
        y3.x /= n3; y3.y /= n3; y3.z /= n3; y3.w /= n3;
    }
    {
        int sc = cst ^ (4 * kq);
        Ys[0][kq * 4 + 0][sc] = y0.x; Ys[0][kq * 4 + 1][sc] = y0.y;
        Ys[0][kq * 4 + 2][sc] = y0.z; Ys[0][kq * 4 + 3][sc] = y0.w;
        sc = (cst + 32) ^ (4 * kq);
        Ys[0][kq * 4 + 0][sc] = y1.x; Ys[0][kq * 4 + 1][sc] = y1.y;
        Ys[0][kq * 4 + 2][sc] = y1.z; Ys[0][kq * 4 + 3][sc] = y1.w;
        sc = (cst + 64) ^ (4 * kq);
        Ys[0][kq * 4 + 0][sc] = y2.x; Ys[0][kq * 4 + 1][sc] = y2.y;
        Ys[0][kq * 4 + 2][sc] = y2.z; Ys[0][kq * 4 + 3][sc] = y2.w;
        sc = (cst + 96) ^ (4 * kq);
        Ys[0][kq * 4 + 0][sc] = y3.x; Ys[0][kq * 4 + 1][sc] = y3.y;
        Ys[0][kq * 4 + 2][sc] = y3.z; Ys[0][kq * 4 + 3][sc] = y3.w;
    }
    __syncthreads();

    float acc[4][4];
    int cur = 0;

#pragma unroll 1
    for (int s = 0; s < NSTAGE; ++s) {
        const int ct = s >> 3;
        const int kc = s & 7;

        if (s + 1 < NSTAGE) {
            const int ct1 = (s + 1) >> 3;
            const int kc1 = (s + 1) & 7;
            const float* base = Yb + (size_t)(ct1 * 128 + cst) * CC + kc1 * KC + kq * 4;
            y0 = *(const float4*)(base);
            y1 = *(const float4*)(base + 32 * CC);
            y2 = *(const float4*)(base + 64 * CC);
            y3 = *(const float4*)(base + 96 * CC);
            int cb = b * NYY + ct1 * 128 + cst;
            float n0 = ny[cb], n1 = ny[cb + 32], n2 = ny[cb + 64], n3 = ny[cb + 96];
            y0.x /= n0; y0.y /= n0; y0.z /= n0; y0.w /= n0;
            y1.x /= n1; y1.y /= n1; y1.z /= n1; y1.w /= n1;
            y2.x /= n2; y2.y /= n2; y2.z /= n2; y2.w /= n2;
            y3.x /= n3; y3.y /= n3; y3.z /= n3; y3.w /= n3;
        }

        if (kc == 0) {
#pragma unroll
            for (int i = 0; i < 4; ++i)
#pragma unroll
                for (int j = 0; j < 4; ++j) acc[i][j] = 0.f;
        }

#pragma unroll
        for (int k4 = 0; k4 < 8; ++k4) {
            const int swz = 4 * k4;
            float4 xq[4], yq[4];
#pragma unroll
            for (int i = 0; i < 4; ++i)
                xq[i] = *(const float4*)(&Xs[r0 + i][kc * KC + k4 * 4]);
#pragma unroll
            for (int kk = 0; kk < 4; ++kk)
                yq[kk] = *(const float4*)(&Ys[cur][k4 * 4 + kk][c0 ^ swz]);
#pragma unroll
            for (int kk = 0; kk < 4; ++kk) {
#pragma unroll
                for (int i = 0; i < 4; ++i) {
                    float xv = ((const float*)&xq[i])[kk];
                    acc[i][0] = fmaf(xv, yq[kk].x, acc[i][0]);
                    acc[i][1] = fmaf(xv, yq[kk].y, acc[i][1]);
                    acc[i][2] = fmaf(xv, yq[kk].z, acc[i][2]);
                    acc[i][3] = fmaf(xv, yq[kk].w, acc[i][3]);
                }
            }
        }

        if (kc == NKC - 1) {
            const int cbase = ct * 128;
#pragma unroll 1
            for (int rr = 0; rr < 4; ++rr) {
                float th = thr[r0 + rr];
#pragma unroll
                for (int j = 0; j < 4; ++j) {
                    float v = acc[rr][j];
                    if (v >= th) {
                        int p = atomicAdd(&qn, 1);
                        if (p < QMAX) {
                            qv[p] = v;
                            qm[p] = ((r0 + rr) << 13) | (cbase + c0 + j);
                        }
                    }
                }
                __syncthreads();
                if (t < TM) {
                    int n = qn;
                    if (n > QMAX) n = QMAX;
#pragma unroll 1
                    for (int e = 0; e < n; ++e) {
                        int m = qm[e];
                        if ((m >> 13) == t) {
                            float v = qv[e];
                            int col = m & 8191;
                            float lv = topv[t][KP - 1];
                            int li = topi[t][KP - 1];
                            if (v > lv || (v == lv && col < li)) {
                                int p = KP - 1;
                                while (p > 0 && (topv[t][p - 1] < v ||
                                       (topv[t][p - 1] == v && topi[t][p - 1] > col))) {
                                    topv[t][p] = topv[t][p - 1];
                                    topi[t][p] = topi[t][p - 1];
                                    --p;
                                }
                                topv[t][p] = v;
                                topi[t][p] = col;
                            }
                        }
                    }
                    thr[t] = topv[t][KP - 1];
                }
                __syncthreads();
                if (t == 0) qn = 0;
                __syncthreads();
            }
        }

        if (s + 1 < NSTAGE) {
            const int bn = cur ^ 1;
            int sc = cst ^ (4 * kq);
            Ys[bn][kq * 4 + 0][sc] = y0.x; Ys[bn][kq * 4 + 1][sc] = y0.y;
            Ys[bn][kq * 4 + 2][sc] = y0.z; Ys[bn][kq * 4 + 3][sc] = y0.w;
            sc = (cst + 32) ^ (4 * kq);
            Ys[bn][kq * 4 + 0][sc] = y1.x; Ys[bn][kq * 4 + 1][sc] = y1.y;
            Ys[bn][kq * 4 + 2][sc] = y1.z; Ys[bn][kq * 4 + 3][sc] = y1.w;
            sc = (cst + 64) ^ (4 * kq);
            Ys[bn][kq * 4 + 0][sc] = y2.x; Ys[bn][kq * 4 + 1][sc] = y2.y;
            Ys[bn][kq * 4 + 2][sc] = y2.z; Ys[bn][kq * 4 + 3][sc] = y2.w;
            sc = (cst + 96) ^ (4 * kq);
            Ys[bn][kq * 4 + 0][sc] = y3.x; Ys[bn][kq * 4 + 1][sc] = y3.y;
            Ys[bn][kq * 4 + 2][sc] = y3.z; Ys[bn][kq * 4 + 3][sc] = y3.w;
        }
        __syncthreads();
        cur ^= 1;
    }

    if (t < TM) {
        int gr = b * NXX + row0 + t;
        float simv[KP];
        int id[KP];
        bool used[KP];
#pragma unroll
        for (int j = 0; j < KP; ++j) {
            simv[j] = topv[t][j] / TAUF;
            id[j] = topi[t][j];
            used[j] = false;
        }
        float sv[NSLOT];
        int si[NSLOT];
#pragma unroll 1
        for (int k = 0; k < NSLOT; ++k) {
            float bv = -INFINITY;
            int bi = 0x7fffffff, bj = 0;
#pragma unroll 1
            for (int j = 0; j < KP; ++j) {
                if (!used[j]) {
                    if (simv[j] > bv || (simv[j] == bv && id[j] < bi)) {
                        bv = simv[j]; bi = id[j]; bj = j;
                    }
                }
            }
            used[bj] = true;
            sv[k] = bv;
            si[k] = bi;
        }
        float mg = INFINITY;
        int ms = 0;
#pragma unroll 1
        for (int sl = 0; sl < KNN; ++sl) {
            float g = sv[sl] - sv[sl + 1];
            if (g > 0.f && g < mg) { mg = g; ms = sl; }
        }
#pragma unroll
        for (int k = 0; k < NSLOT; ++k) {
            rowSim[(size_t)gr * NSLOT + k] = sv[k];
            rowIdx[(size_t)gr * NSLOT + k] = si[k];
        }
        rowGap[gr] = mg;
        rowSlot[gr] = ms;
    }
}

// ---- global argmin of (gap, row) ----
__global__ __launch_bounds__(256) void argmin_kernel(const float* __restrict__ rowGap,
                                                     const int* __restrict__ rowSlot,
                                                     int* __restrict__ sel) {
    __shared__ float gbuf[256];
    __shared__ int rbuf[256];
    const int t = threadIdx.x;
    float bg = INFINITY;
    int br = 0x7fffffff;
    for (int r = t; r < BB * NXX; r += 256) {
        float g = rowGap[r];
        if (g < bg || (g == bg && r < br)) { bg = g; br = r; }
    }
    gbuf[t] = bg;
    rbuf[t] = br;
    __syncthreads();
    for (int off = 128; off; off >>= 1) {
        if (t < off) {
            float g2 = gbuf[t + off];
            int r2 = rbuf[t + off];
            if (g2 < gbuf[t] || (g2 == gbuf[t] && r2 < rbuf[t])) {
                gbuf[t] = g2; rbuf[t] = r2;
            }
        }
        __syncthreads();
    }
    if (t == 0) {
        sel[0] = rbuf[0];
        sel[1] = (rbuf[0] < BB * NXX) ? rowSlot[rbuf[0]] : 0;
    }
}

// ---- final: anti-true swap at the selected site, softmax, write ----
__global__ __launch_bounds__(256) void final_kernel(const float* __restrict__ rowSim,
                                                    const int* __restrict__ rowIdx,
                                                    const int* __restrict__ sel,
                                                    float* __restrict__ out_vals,
                                                    float* __restrict__ out_idx) {
    const int r = blockIdx.x * 256 + threadIdx.x;
    float sv[NSLOT];
    int si[NSLOT];
#pragma unroll
    for (int k = 0; k < NSLOT; ++k) {
        sv[k] = rowSim[(size_t)r * NSLOT + k];
        si[k] = rowIdx[(size_t)r * NSLOT + k];
    }
    const int selRow = sel[0];
    const int selSlot = sel[1];
    if (r == selRow) {
        if (selSlot < KNN - 1) {
            float tv = sv[selSlot]; sv[selSlot] = sv[selSlot + 1]; sv[selSlot + 1] = tv;
            int ti = si[selSlot]; si[selSlot] = si[selSlot + 1]; si[selSlot + 1] = ti;
        } else {
            sv[KNN - 1] = sv[KNN];
            si[KNN - 1] = si[KNN];
        }
    }
    float m = sv[0];
#pragma unroll
    for (int k = 1; k < KNN; ++k) m = fmaxf(m, sv[k]);
    float e[KNN];
    float sum = 0.f;
#pragma unroll
    for (int k = 0; k < KNN; ++k) { e[k] = expf(sv[k] - m); sum += e[k]; }
    float inv = 1.f / sum;
#pragma unroll
    for (int k = 0; k < KNN; ++k) {
        out_vals[(size_t)r * KNN + k] = e[k] * inv;
        out_idx[(size_t)r * KNN + k] = (float)si[k];
    }
}

extern "C" void kernel_launch(void* const* d_in, const int* in_sizes, int n_in,
                              void* d_out, int out_size, void* d_ws, size_t ws_size,
                              hipStream_t stream) {
    (void)in_sizes; (void)n_in; (void)out_size;
    const float* fx = (const float*)d_in[0];
    const float* fy = (const float*)d_in[1];

    float* nx = (float*)d_ws;
    float* ny = nx + BB * NXX;
    float* rowSim = ny + BB * NYY;
    int* rowIdx = (int*)(rowSim + (size_t)BB * NXX * NSLOT);
    float* rowGap = (float*)(rowIdx + (size_t)BB * NXX * NSLOT);
    int* rowSlot = (int*)(rowGap + BB * NXX);
    int* sel = rowSlot + BB * NXX;
    float* Ynt = (float*)(sel + 16);

    size_t need_fast = (size_t)((char*)(Ynt + (size_t)BB * CC * YSTR) - (char*)d_ws);
    bool fast = ws_size >= need_fast;

    float* out_vals = (float*)d_out;
    float* out_idx = out_vals + (size_t)BB * NXX * KNN;

    norms_kernel<<<(BB * NXX + BB * NYY) / 256, 256, 0, stream>>>(fx, fy, nx, ny);
    if (fast) {
        ytranspose<<<BB * 128 * 4, 256, 0, stream>>>(fy, ny, Ynt);
        pass1_fast<<<BB * (NXX / TM), 256, 0, stream>>>(fx, nx, Ynt,
                                                        rowSim, rowIdx, rowGap, rowSlot);
    } else {
        pass1_slow<<<BB * (NXX / TM), 256, 0, stream>>>(fx, fy, nx, ny,
                                                        rowSim, rowIdx, rowGap, rowSlot);
    }
    argmin_kernel<<<1, 256, 0, stream>>>(rowGap, rowSlot, sel);
    final_kernel<<<(BB * NXX) / 256, 256, 0, stream>>>(rowSim, rowIdx, sel, out_vals, out_idx);
}